// Round 4
// baseline (556.034 us; speedup 1.0000x reference)
//
#include <hip/hip_runtime.h>
#include <hip/hip_bf16.h>
#include <stdint.h>
#include <stddef.h>

#define NN 8192
#define DD 128
#define PADW 136  // LDS sim row stride (bf16): breaks power-of-2 bank conflicts

typedef __attribute__((ext_vector_type(8))) short bf16x8;
typedef __attribute__((ext_vector_type(4))) float f32x4;

static __device__ __forceinline__ unsigned short f2bf(float x) {
  __hip_bfloat16 h = __float2bfloat16(x);
  return *(unsigned short*)&h;
}
static __device__ __forceinline__ float bf2f(short u) {
  return __uint_as_float(((unsigned int)(unsigned short)u) << 16);
}

// ---------------------------------------------------------------------------
// Kernel 1: row-normalize features (fp32) and cast to bf16. One wave per row.
// ---------------------------------------------------------------------------
__global__ __launch_bounds__(256) void normalize_kernel(
    const float* __restrict__ f, __hip_bfloat16* __restrict__ fn) {
  const int wave = threadIdx.x >> 6;
  const int lane = threadIdx.x & 63;
  const int row = blockIdx.x * 4 + wave;
  const float2 v = ((const float2*)(f + (size_t)row * DD))[lane];
  float ss = v.x * v.x + v.y * v.y;
#pragma unroll
  for (int m = 1; m < 64; m <<= 1) ss += __shfl_xor(ss, m, 64);
  const float inv = 1.0f / fmaxf(sqrtf(ss), 1e-8f);
  __hip_bfloat162 o;
  o.x = __float2bfloat16(v.x * inv);
  o.y = __float2bfloat16(v.y * inv);
  ((__hip_bfloat162*)(fn + (size_t)row * DD))[lane] = o;
}

// ---------------------------------------------------------------------------
// Kernel 2: block = 128 rows x 1024 cols = 8 J-tiles of 128.
// Per tile: GEMM (bf16 MFMA, swapped operands, frags from L2) -> exp -> LDS,
// then phase 3 with depth-2 rotating register prefetch of the masks and
// persistent per-row accumulators (reduce + atomics ONCE per block).
// Mask loads for tile t+1's first 2 subiters are issued during tile t's
// phase-3 tail so they cross the barrier+GEMM window already in flight.
// ---------------------------------------------------------------------------
__global__ __launch_bounds__(256, 2) void ssnt_main(
    const __hip_bfloat16* __restrict__ fn,
    const int* __restrict__ pmask,
    const int* __restrict__ nmask,
    float* __restrict__ pos, float* __restrict__ neg, float* __restrict__ cnt) {
  __shared__ __hip_bfloat16 sim[128 * PADW];  // 34 KB

  const int tid = threadIdx.x;
  const int lane = tid & 63;
  const int quad = lane >> 4;
  const int l16 = lane & 15;
  const int wx = (tid >> 6) & 1;
  const int wy = tid >> 7;

  const int I0g = blockIdx.y * 128;        // row-strip base
  const int Jbase = blockIdx.x * 1024;     // col-span base (8 tiles)
  const int I0 = I0g + wy * 64;

  // phase-3 mapping: thread -> (rGrp, cl); row iG = I0g + it*16 + rGrp
  const int rGrp = tid >> 4;
  const int cl = tid & 15;
  // mask element offset for (it, tile t): baseOff + it*16*NN + t*128
  const size_t baseOff = (size_t)(I0g + rGrp) * NN + cl * 8 + Jbase;

  // persistent per-row accumulators (8 rows per thread)
  float accP[8] = {0.f, 0.f, 0.f, 0.f, 0.f, 0.f, 0.f, 0.f};
  float accQ[8] = {0.f, 0.f, 0.f, 0.f, 0.f, 0.f, 0.f, 0.f};
  int accC[8] = {0, 0, 0, 0, 0, 0, 0, 0};

  // rotation slots: [parity][half]; each subiter needs 2 int4 per mask
  int4 bP[2][2], bN[2][2];
  {  // prologue: prefetch tile 0, subiters 0 and 1
    const size_t o0 = baseOff;                     // it=0
    const size_t o1 = baseOff + (size_t)16 * NN;   // it=1
    bP[0][0] = *(const int4*)(pmask + o0);
    bP[0][1] = *(const int4*)(pmask + o0 + 4);
    bN[0][0] = *(const int4*)(nmask + o0);
    bN[0][1] = *(const int4*)(nmask + o0 + 4);
    bP[1][0] = *(const int4*)(pmask + o1);
    bP[1][1] = *(const int4*)(pmask + o1 + 4);
    bN[1][0] = *(const int4*)(nmask + o1);
    bN[1][1] = *(const int4*)(nmask + o1 + 4);
  }

  const float tinv = 1.0f / 0.07f;
  const bool diagBlock = ((blockIdx.y >> 3) == blockIdx.x);
  const int diagT = blockIdx.y & 7;  // tile index containing the diagonal

  for (int t = 0; t < 8; ++t) {
    const int J0t = Jbase + t * 128;
    const int J0 = J0t + wx * 64;

    // ---- Phase 1: GEMM (64x64 per wave), fragments from L2 ----
    f32x4 acc[4][4] = {};
#pragma unroll
    for (int kt = 0; kt < 4; ++kt) {
      const int ko = kt * 32 + quad * 8;
      bf16x8 aF[4], bF[4];
#pragma unroll
      for (int mt = 0; mt < 4; ++mt)
        aF[mt] = *(const bf16x8*)(fn + (size_t)(I0 + mt * 16 + l16) * DD + ko);
#pragma unroll
      for (int nt = 0; nt < 4; ++nt)
        bF[nt] = *(const bf16x8*)(fn + (size_t)(J0 + nt * 16 + l16) * DD + ko);
#pragma unroll
      for (int mt = 0; mt < 4; ++mt)
#pragma unroll
        for (int nt = 0; nt < 4; ++nt)
          acc[mt][nt] = __builtin_amdgcn_mfma_f32_16x16x32_bf16(
              bF[nt], aF[mt], acc[mt][nt], 0, 0, 0);  // SWAPPED operands
    }

    // ---- Phase 2: exp -> LDS (bf16) ----
#pragma unroll
    for (int mt = 0; mt < 4; ++mt) {
      const int iLoc = wy * 64 + mt * 16 + l16;
#pragma unroll
      for (int nt = 0; nt < 4; ++nt) {
        const int jLoc = wx * 64 + nt * 16 + quad * 4;
        ushort4 w;
        w.x = f2bf(__expf(acc[mt][nt][0] * tinv));
        w.y = f2bf(__expf(acc[mt][nt][1] * tinv));
        w.z = f2bf(__expf(acc[mt][nt][2] * tinv));
        w.w = f2bf(__expf(acc[mt][nt][3] * tinv));
        *(ushort4*)(sim + iLoc * PADW + jLoc) = w;
      }
    }
    __syncthreads();

    // ---- Phase 3: masked accumulate, depth-2 rotating prefetch ----
    const bool diagTile = diagBlock && (t == diagT);
#pragma unroll
    for (int it = 0; it < 8; ++it) {
      const int s = it & 1;
      // consume-copies (SSA renames, no real moves)
      int4 cpa = bP[s][0], cpb = bP[s][1];
      int4 cna = bN[s][0], cnb = bN[s][1];
      // refill the slot: subiter it+2 of this tile, or subiter it-6 of tile t+1
      if (it < 6) {
        const size_t o = baseOff + (size_t)(it + 2) * 16 * NN + t * 128;
        bP[s][0] = *(const int4*)(pmask + o);
        bP[s][1] = *(const int4*)(pmask + o + 4);
        bN[s][0] = *(const int4*)(nmask + o);
        bN[s][1] = *(const int4*)(nmask + o + 4);
      } else if (t + 1 < 8) {
        const size_t o = baseOff + (size_t)(it - 6) * 16 * NN + (t + 1) * 128;
        bP[s][0] = *(const int4*)(pmask + o);
        bP[s][1] = *(const int4*)(pmask + o + 4);
        bN[s][0] = *(const int4*)(nmask + o);
        bN[s][1] = *(const int4*)(nmask + o + 4);
      }
      // zero self-contrast (block-uniform branch; 1/64 of blocks, 1/8 tiles)
      if (diagTile) {
        const int d = (I0g + it * 16 + rGrp) - (J0t + cl * 8);
#pragma unroll
        for (int r = 0; r < 4; ++r) {
          if (d == r) { (&cpa.x)[r] = 0; (&cna.x)[r] = 0; }
          if (d == r + 4) { (&cpb.x)[r] = 0; (&cnb.x)[r] = 0; }
        }
      }
      const int rLoc = it * 16 + rGrp;
      const bf16x8 ev = *(const bf16x8*)(sim + rLoc * PADW + cl * 8);
      float p = accP[it], q = accQ[it];
      int c = accC[it];
#pragma unroll
      for (int r = 0; r < 8; ++r) {
        const int pm = (r < 4) ? (&cpa.x)[r] : (&cpb.x)[r - 4];
        const int nm = (r < 4) ? (&cna.x)[r] : (&cnb.x)[r - 4];
        const float e = bf2f(ev[r]);
        p = fmaf(e, (float)pm, p);
        q = fmaf(e, (float)nm, q);
        c += pm;
      }
      accP[it] = p; accQ[it] = q; accC[it] = c;
    }
    __syncthreads();  // sim reused next tile
  }

  // ---- Epilogue: reduce over the 16 col-lanes, one atomic set per row ----
#pragma unroll
  for (int it = 0; it < 8; ++it) {
    float p = accP[it], q = accQ[it], c = (float)accC[it];
#pragma unroll
    for (int m = 1; m < 16; m <<= 1) {
      p += __shfl_xor(p, m, 64);
      q += __shfl_xor(q, m, 64);
      c += __shfl_xor(c, m, 64);
    }
    const int iG = I0g + it * 16 + rGrp;
    if (cl == 0) atomicAdd(&pos[iG], p);
    else if (cl == 1) atomicAdd(&neg[iG], q);
    else if (cl == 2) atomicAdd(&cnt[iG], c);
  }
}

// ---------------------------------------------------------------------------
// Kernel 3: loss = -mean(log(pos/(pos+neg)) / cnt)
// ---------------------------------------------------------------------------
__global__ __launch_bounds__(256) void finalize_kernel(
    const float* __restrict__ pos, const float* __restrict__ neg,
    const float* __restrict__ cnt, float* __restrict__ out) {
  float s = 0.f;
  for (int i = threadIdx.x; i < NN; i += 256) {
    const float p = pos[i];
    const float q = neg[i];
    s += logf(p / (p + q)) / cnt[i];
  }
#pragma unroll
  for (int m = 1; m < 64; m <<= 1) s += __shfl_xor(s, m, 64);
  __shared__ float wsum[4];
  if ((threadIdx.x & 63) == 0) wsum[threadIdx.x >> 6] = s;
  __syncthreads();
  if (threadIdx.x == 0) {
    out[0] = -(wsum[0] + wsum[1] + wsum[2] + wsum[3]) / (float)NN;
  }
}

extern "C" void kernel_launch(void* const* d_in, const int* in_sizes, int n_in,
                              void* d_out, int out_size, void* d_ws, size_t ws_size,
                              hipStream_t stream) {
  const float* features = (const float*)d_in[0];
  const int* pmask = (const int*)d_in[1];
  const int* nmask = (const int*)d_in[2];
  float* out = (float*)d_out;

  char* ws = (char*)d_ws;
  __hip_bfloat16* fn = (__hip_bfloat16*)ws;  // 2 MB
  float* pos = (float*)(ws + (size_t)NN * DD * sizeof(__hip_bfloat16));
  float* neg = pos + NN;
  float* cnt = neg + NN;

  hipMemsetAsync(pos, 0, 3 * (size_t)NN * sizeof(float), stream);
  normalize_kernel<<<NN / 4, 256, 0, stream>>>(features, fn);
  ssnt_main<<<dim3(8, 64), 256, 0, stream>>>(fn, pmask, nmask, pos, neg, cnt);
  finalize_kernel<<<1, 256, 0, stream>>>(pos, neg, cnt, out);
}